// Round 4
// baseline (629.066 us; speedup 1.0000x reference)
//
#include <hip/hip_runtime.h>
#include <stdint.h>

// BridgeoutFcLayer forward, training path. Bit-exact vs JAX with
// jax_threefry_partitionable=True (verified: absmax 0.0 in R2/R3):
//   per element i (linear idx over (256,1024,1024)):
//     (b1,b2) = threefry2x32(key=(0,42), hi=0, lo=i);  bits = b1 ^ b2
//     keep <=> MSB(bits)==0
//   w_eff = w + sign_inject(MSB(bits), |w|)
//
// VALU-bound. This revision:
//  - key-injection fused into next round's add (v_add3_u32 pattern):
//    {v0+=K0; v1+=K1; v0+=v1} -> {t=v1+K1; v0=v0+v1+(K0+K1)}  (saves 4/hash)
//  - 1 output element/thread, 1024 blocks (4/CU = 16 waves/CU, 2x occupancy)
//  - K-loop unroll 4 = 4 independent hash chains in flight per thread

__device__ __forceinline__ uint32_t rotl_ab(uint32_t x, uint32_t r) {
  return __builtin_amdgcn_alignbit(x, x, 32u - r);  // rotl == rotr(32-r)
}

#define TF_R(r)                         \
  {                                     \
    v0 += v1;                           \
    v1 = rotl_ab(v1, r) ^ v0;           \
  }

// Injection-fused round: inject (Kv0, Kv1) then do round r.
#define TF_R_INJ(r, Kv0, Kv1)           \
  {                                     \
    uint32_t t = v1 + (Kv1);            \
    v0 = v0 + v1 + ((Kv0) + (Kv1));     \
    v1 = rotl_ab(t, r) ^ v0;            \
  }

// threefry2x32, key (0,42), counter (0,c); returns word0 ^ word1.
__device__ __forceinline__ uint32_t tf_bits_0_42(uint32_t c) {
  const uint32_t KS1 = 42u;
  const uint32_t KS2 = 0x1BD11BF0u;  // 0 ^ 42 ^ 0x1BD11BDA

  uint32_t v1 = c + KS1;     // x2(lo) + ks1
  uint32_t v0 = v1;          // round 1: v0 = 0 + v1
  v1 = rotl_ab(v1, 13) ^ v0;
  TF_R(15) TF_R(26) TF_R(6)
  TF_R_INJ(17, KS1, KS2 + 1u)          // inj after r4
  TF_R(29) TF_R(16) TF_R(24)
  TF_R_INJ(13, KS2, 2u)                // inj after r8  (+ks0+2)
  TF_R(15) TF_R(26) TF_R(6)
  TF_R_INJ(17, 0u, KS1 + 3u)           // inj after r12 (ks0 = 0)
  TF_R(29) TF_R(16) TF_R(24)
  TF_R_INJ(13, KS1, KS2 + 4u)          // inj after r16
  TF_R(15) TF_R(26) TF_R(6)
  v0 += KS2;                           // final inj
  v1 += 5u;
  return v0 ^ v1;
}

// pert = sign(bits) | |w|  (v_bfi_b32 / v_and_or_b32 pattern)
__device__ __forceinline__ float sign_inject(uint32_t bits, float w) {
  uint32_t r = (bits & 0x80000000u) | (__float_as_uint(w) & 0x7FFFFFFFu);
  return __uint_as_float(r);
}

__global__ __launch_bounds__(256) void BridgeoutFcLayer_60413009985793_kernel(
    const float* __restrict__ x, const float* __restrict__ weight,
    const float* __restrict__ bias, float* __restrict__ out) {
  const int oc = blockIdx.x & 3;        // 256-wide output chunk
  const int b  = blockIdx.x >> 2;       // 0..255
  const int o  = (oc << 8) + threadIdx.x;

  // Stage this block's single x row; reads are wave-uniform LDS broadcasts.
  __shared__ float xs[1024];
  for (int t = threadIdx.x; t < 1024; t += 256) xs[t] = x[t + (b << 10)];
  __syncthreads();

  float acc = 0.0f;
  uint32_t cbase = ((uint32_t)b << 20) + (uint32_t)o;  // element (b, 0, o)
  const float* wp = weight + o;

  for (int i = 0; i < 1024; i += 4) {
    // 4 independent hash chains in flight (different i => independent)
#pragma unroll 4
    for (int u = 0; u < 4; ++u) {
      float w = wp[u << 10];
      uint32_t bits = tf_bits_0_42(cbase + (u << 10));
      acc = fmaf(xs[i + u], w + sign_inject(bits, w), acc);
    }
    cbase += 4096u;
    wp += 4096;
  }

  out[(b << 10) + o] = acc + bias[o];
}

extern "C" void kernel_launch(void* const* d_in, const int* in_sizes, int n_in,
                              void* d_out, int out_size, void* d_ws, size_t ws_size,
                              hipStream_t stream) {
  const float* x      = (const float*)d_in[0];
  const float* weight = (const float*)d_in[1];
  const float* bias   = (const float*)d_in[2];
  float* out          = (float*)d_out;

  // 256 b x 4 o-chunks = 1024 blocks of 256 threads (4 blocks/CU)
  BridgeoutFcLayer_60413009985793_kernel<<<1024, 256, 0, stream>>>(x, weight, bias, out);
}

// Round 5
// 500.704 us; speedup vs baseline: 1.2564x; 1.2564x over previous
//
#include <hip/hip_runtime.h>
#include <stdint.h>

// BridgeoutFcLayer forward, training path. Bit-exact vs JAX with
// jax_threefry_partitionable=True (verified: absmax 0.0 in R2/R3/R4):
//   per element i (linear idx over (256,1024,1024)):
//     (b1,b2) = threefry2x32(key=(0,42), hi=0, lo=i);  bits = b1 ^ b2
//     keep <=> MSB(bits)==0
//   w_eff = w + sign_inject(MSB(bits), |w|)
//
// Issue-bound VALU kernel. R3 structure (b-pair, VGPR-32 codegen) + op cuts:
//  - injection rounds fused to 4 ops via v_add3 with SGPR-held constants
//  - counter fully folded into each hash's init literal add
//  - no v_mov in round 1 (SSA renaming)
// R4 lesson: 1-elem/thread unroll-4 collapsed to VGPR=16 codegen (+35% ops).

__device__ __forceinline__ uint32_t rotl_ab(uint32_t x, uint32_t r) {
  return __builtin_amdgcn_alignbit(x, x, 32u - r);  // rotl == rotr(32-r)
}

#define TF_R(r)                         \
  {                                     \
    v0 += v1;                           \
    v1 = rotl_ab(v1, r) ^ v0;           \
  }

// Injection (Kv0,Kv1) fused into the following round r:
//   v0' = v0 + v1 + (Kv0+Kv1)  [v_add3, SGPR const]
//   v1' = rotl(v1 + Kv1, r) ^ v0'
#define TF_R_INJ(r, Kv0, Kv1)           \
  {                                     \
    uint32_t t = v1 + (Kv1);            \
    v0 = v0 + v1 + ((Kv0) + (Kv1));     \
    v1 = rotl_ab(t, r) ^ v0;            \
  }

// threefry2x32, key (0,42), counter (0, base+COFF); returns word0 ^ word1.
// COFF is a compile-time constant so the init is ONE literal add.
__device__ __forceinline__ uint32_t tf_bits_0_42(uint32_t base, uint32_t coff) {
  const uint32_t KS1 = 42u;
  const uint32_t KS2 = 0x1BD11BF0u;  // 0 ^ 42 ^ 0x1BD11BDA

  uint32_t v1 = base + (coff + KS1);   // x2(lo) + ks1, single literal add
  uint32_t v0 = v1;                    // round 1: v0 = 0 + v1 (rename, no mov)
  v1 = rotl_ab(v1, 13) ^ v0;
  TF_R(15) TF_R(26) TF_R(6)
  TF_R_INJ(17, KS1, KS2 + 1u)          // inject after round 4
  TF_R(29) TF_R(16) TF_R(24)
  TF_R_INJ(13, KS2, 2u)                // inject after round 8  (+ks0+2)
  TF_R(15) TF_R(26) TF_R(6)
  TF_R_INJ(17, 0u, KS1 + 3u)           // inject after round 12 (ks0 = 0)
  TF_R(29) TF_R(16) TF_R(24)
  TF_R_INJ(13, KS1, KS2 + 4u)          // inject after round 16
  TF_R(15) TF_R(26) TF_R(6)
  v0 += KS2;                           // final injection
  v1 += 5u;
  return v0 ^ v1;
}

// pert = sign(bits) | |w|  (single v_bfi_b32)
__device__ __forceinline__ float sign_inject(uint32_t bits, float w) {
  uint32_t r = (bits & 0x80000000u) | (__float_as_uint(w) & 0x7FFFFFFFu);
  return __uint_as_float(r);
}

__global__ __launch_bounds__(256, 2) void BridgeoutFcLayer_60413009985793_kernel(
    const float* __restrict__ x, const float* __restrict__ weight,
    const float* __restrict__ bias, float* __restrict__ out) {
  const int oc = blockIdx.x & 3;        // 256-wide output chunk
  const int b  = blockIdx.x >> 2;       // 0..127 (block also does b+128)
  const int o  = (oc << 8) + threadIdx.x;

  // Stage the two x rows; loop reads are wave-uniform LDS broadcasts.
  __shared__ float xs0[1024];
  __shared__ float xs1[1024];
  for (int t = threadIdx.x; t < 1024; t += 256) {
    xs0[t] = x[t + (b << 10)];
    xs1[t] = x[t + ((b + 128) << 10)];
  }
  __syncthreads();

  float acc0 = 0.0f, acc1 = 0.0f;
  uint32_t cbase = ((uint32_t)b << 20) + (uint32_t)o;  // element (b, 0, o)
  const float* wp = weight + o;

#pragma unroll 2
  for (int i = 0; i < 1024; i += 4) {
#pragma unroll 4
    for (int u = 0; u < 4; ++u) {
      float w = wp[u << 10];                               // shared by b-pair
      uint32_t bits0 = tf_bits_0_42(cbase, (uint32_t)(u << 10));
      uint32_t bits1 = tf_bits_0_42(cbase, (uint32_t)(u << 10) + 0x08000000u);
      acc0 = fmaf(xs0[i + u], w + sign_inject(bits0, w), acc0);
      acc1 = fmaf(xs1[i + u], w + sign_inject(bits1, w), acc1);
    }
    cbase += 4096u;
    wp += 4096;
  }

  float bo = bias[o];
  out[(b << 10) + o]         = acc0 + bo;
  out[((b + 128) << 10) + o] = acc1 + bo;
}

extern "C" void kernel_launch(void* const* d_in, const int* in_sizes, int n_in,
                              void* d_out, int out_size, void* d_ws, size_t ws_size,
                              hipStream_t stream) {
  const float* x      = (const float*)d_in[0];
  const float* weight = (const float*)d_in[1];
  const float* bias   = (const float*)d_in[2];
  float* out          = (float*)d_out;

  // 128 b-pairs x 4 o-chunks = 512 blocks of 256 threads
  BridgeoutFcLayer_60413009985793_kernel<<<512, 256, 0, stream>>>(x, weight, bias, out);
}